// Round 4
// baseline (39.484 us; speedup 1.0000x reference)
//
#include <hip/hip_runtime.h>
#include <hip/hip_cooperative_groups.h>
#include <math.h>

namespace cg = cooperative_groups;

// Problem constants (from reference setup_inputs):
//   X: (B=32, A=3, S=52, S=52, D=85) f32 ; yboxes: (32,20,4) f32 ;
//   ylabels: (32,20) i32 ; anchors: (3,2) f32 ; nclasses=80
// Reference quirk: wgrid = X.shape[-4] = A = 3 (NOT 52); hgrid = 52.
#define BB    32
#define AA    3
#define SS    52
#define DD    85
#define NN    20
#define NCLS  80
#define KK    (BB * NN)          // 640 boxes
#define WGRID 3
#define HGRID 52
#define HW    (HGRID * WGRID)    // 156 cells
#define BIGV  (1 << 30)
#define NEGINF (-__builtin_inff())
#define NTASK (HW * AA)          // 468 (cell, anchor) tasks = 468 waves
#define NBLOCKS (NTASK / 4)      // 117 blocks x 4 waves

// Single cooperative kernel:
//   phase A (per block, redundant, no communication): build first[156] in LDS
//     from all 640 boxes (boxes also stashed in LDS).
//   phase B: wave w = (cell, anchor) computes its loss term, lane 0 writes a
//     partial to ws[w] (all 468 slots written -> poison-safe).
//   grid.sync()
//   phase C: block 0 reduces the 468 partials, plain store to out[0].
__global__ void __launch_bounds__(256)
yolo_coop_kernel(const float* __restrict__ X,
                 const float* __restrict__ yboxes,
                 const int* __restrict__ ylabels,
                 const float* __restrict__ anchors,
                 float* __restrict__ wsf,
                 float* __restrict__ out) {
    __shared__ float4 sbox[KK];     // 10 KB
    __shared__ int    first[HW];    // 624 B
    __shared__ float  sred[4];

    const int tid  = threadIdx.x;
    const int lane = tid & 63;

    // ---- phase A: redundant per-block prep ----
    if (tid < HW) first[tid] = BIGV;
    __syncthreads();
    const float4* __restrict__ b4 = (const float4*)yboxes;
#pragma unroll
    for (int k = tid; k < KK; k += 256) {
        float4 b = b4[k];
        sbox[k] = b;
        int x = (int)floorf(b.x * (float)WGRID);   // [0,2]
        int y = (int)floorf(b.y * (float)HGRID);   // [0,51]
        atomicMin(&first[y * WGRID + x], k);
    }
    __syncthreads();

    // ---- phase B: one wave per (cell, anchor) task ----
    const int w    = blockIdx.x * 4 + (tid >> 6);  // 0..467
    const int cell = w / 3;
    const int a    = w - 3 * cell;

    float per = 0.0f;
    const int k = first[cell];
    if (k < BIGV) {
        const float4 bb = sbox[k];
        const int lab = ylabels[k];
        const float2 anc = ((const float2*)anchors)[a];

        const int x = (int)floorf(bb.x * (float)WGRID);
        const int y = (int)floorf(bb.y * (float)HGRID);
        const int img = k / NN;

        const float* __restrict__ P =
            X + ((((size_t)img * AA + a) * SS + y) * SS + x) * DD;

        // coalesced row gather: lane l holds p[l]; lanes 0..20 also p[64+l]
        float e0 = P[lane];
        float e1 = (lane < 21) ? P[64 + lane] : NEGINF;

        // max over class logits p[5..84]
        float v = fmaxf((lane >= 5) ? e0 : NEGINF, (lane < 21) ? e1 : NEGINF);
#pragma unroll
        for (int m = 1; m < 64; m <<= 1) v = fmaxf(v, __shfl_xor(v, m, 64));
        const float mx = v;

        // sum of exp(class - mx)
        float s = ((lane >= 5) ? expf(e0 - mx) : 0.0f) +
                  ((lane < 21) ? expf(e1 - mx) : 0.0f);
#pragma unroll
        for (int m = 1; m < 64; m <<= 1) s += __shfl_xor(s, m, 64);

        // selected class logit (wave-uniform dynamic index -> shuffle)
        const int idx = 5 + lab;                   // 5..84
        const float plab = (idx < 64) ? __shfl(e0, idx, 64)
                                      : __shfl(e1, idx - 64, 64);

        const float p0 = __shfl(e0, 0, 64);
        const float p1 = __shfl(e0, 1, 64);
        const float p2 = __shfl(e0, 2, 64);
        const float p3 = __shfl(e0, 3, 64);
        const float p4 = __shfl(e0, 4, 64);

        // obj = softplus(-p0), numerically stable
        const float z = -p0;
        const float obj = fmaxf(z, 0.0f) + log1pf(expf(-fabsf(z)));

        // box MSE vs target
        const float xrel = bb.x * (float)WGRID - (float)x;
        const float yrel = bb.y * (float)HGRID - (float)y;
        const float wc = bb.z / anc.x;
        const float hc = bb.w / anc.y;
        const float d1 = p1 - xrel, d2 = p2 - yrel;
        const float d3 = p3 - wc,   d4 = p4 - hc;
        const float boxl = 0.25f * (d1 * d1 + d2 * d2 + d3 * d3 + d4 * d4);

        // class NLL
        const float clsl = -(plab - mx - logf(s));

        per = obj + 10.0f * boxl + clsl;
    }
    if (lane == 0) wsf[w] = per;
    __threadfence();

    // ---- grid-wide barrier ----
    cg::this_grid().sync();

    // ---- phase C: block 0 reduces 468 partials ----
    if (blockIdx.x == 0) {
        float v = wsf[tid];                        // tid < 256 <= 467
        const int t2 = tid + 256;
        if (t2 < NTASK) v += wsf[t2];
#pragma unroll
        for (int off = 32; off > 0; off >>= 1) v += __shfl_down(v, off, 64);
        if (lane == 0) sred[tid >> 6] = v;
        __syncthreads();
        if (tid == 0) out[0] = sred[0] + sred[1] + sred[2] + sred[3];
    }
}

extern "C" void kernel_launch(void* const* d_in, const int* in_sizes, int n_in,
                              void* d_out, int out_size, void* d_ws, size_t ws_size,
                              hipStream_t stream) {
    const float* X       = (const float*)d_in[0];
    const float* yboxes  = (const float*)d_in[1];
    const int*   ylabels = (const int*)d_in[2];
    const float* anchors = (const float*)d_in[3];
    // d_in[4] = nclasses scalar (80), hard-coded above.

    float* out = (float*)d_out;
    float* wsf = (float*)d_ws;   // 468 partials, all written every call

    void* args[] = { (void*)&X, (void*)&yboxes, (void*)&ylabels,
                     (void*)&anchors, (void*)&wsf, (void*)&out };
    hipLaunchCooperativeKernel((const void*)yolo_coop_kernel,
                               dim3(NBLOCKS), dim3(256), args, 0, stream);
}